// Round 1
// 553.045 us; speedup vs baseline: 1.0201x; 1.0201x over previous
//
#include <hip/hip_runtime.h>
#include <hip/hip_bf16.h>

#define N_NODES 65536
#define D_IN 1024
#define D_HID 64
#define N_CLS 32

typedef short short8 __attribute__((ext_vector_type(8)));
typedef float floatx4 __attribute__((ext_vector_type(4)));

// ---------- helpers ----------
__device__ __forceinline__ unsigned short f2bf(float f) {
  union { float f; unsigned u; } cv; cv.f = f;
  unsigned r = (cv.u + 0x7FFFu + ((cv.u >> 16) & 1u)) >> 16;
  return (unsigned short)r;
}
__device__ __forceinline__ float2 bf2f2(unsigned v) {
  union { unsigned u; float f; } a, b;
  a.u = v << 16;
  b.u = v & 0xFFFF0000u;
  return make_float2(a.f, b.f);  // (elem 2l, elem 2l+1)
}

// ---------- count (blocks 0..1023) + W1 transpose->bf16 (blocks 1024..1279) ----------
__global__ void k_count_w1t(const int* __restrict__ dst, int* __restrict__ cnt,
                            const float* __restrict__ w1, unsigned short* __restrict__ w1t,
                            int e4) {
  int b = blockIdx.x;
  if (b >= 1024) {
    int i = (b - 1024) * 256 + threadIdx.x;  // [0, 65536)
    int k = i / D_HID, n = i % D_HID;
    w1t[n * D_IN + k] = f2bf(w1[i]);
    return;
  }
  int i = b * 256 + threadIdx.x;
  if (i < e4) {
    int4 d = ((const int4*)dst)[i];
    // results unused -> no-return atomics, fire-and-forget
    atomicAdd(&cnt[d.x], 1);
    atomicAdd(&cnt[d.y], 1);
    atomicAdd(&cnt[d.z], 1);
    atomicAdd(&cnt[d.w], 1);
  }
}

// ---------- scan phase A: per-block sums ----------
__global__ void k_scan_a(const int* __restrict__ cnt, int* __restrict__ bsum) {
  __shared__ int s[256];
  int t = threadIdx.x;
  s[t] = cnt[blockIdx.x * 256 + t];
  __syncthreads();
  for (int off = 128; off > 0; off >>= 1) {
    if (t < off) s[t] += s[t + off];
    __syncthreads();
  }
  if (t == 0) bsum[blockIdx.x] = s[0];
}

// ---------- scan phase C: inline block-offset reduce + rowptr/cursor/dinv ----------
__global__ void k_scan_c(const int* __restrict__ cnt, const int* __restrict__ bsum,
                         int* __restrict__ rowptr, int* __restrict__ cursor,
                         float* __restrict__ dinv) {
  __shared__ int s[256];
  int t = threadIdx.x;
  s[t] = (t < blockIdx.x) ? bsum[t] : 0;
  __syncthreads();
  for (int off = 128; off > 0; off >>= 1) {
    if (t < off) s[t] += s[t + off];
    __syncthreads();
  }
  int blockoff = s[0];
  __syncthreads();
  int i = blockIdx.x * 256 + t;
  int v = cnt[i];
  s[t] = v;
  __syncthreads();
  for (int off = 1; off < 256; off <<= 1) {
    int x = (t >= off) ? s[t - off] : 0;
    __syncthreads();
    s[t] += x;
    __syncthreads();
  }
  int excl = s[t] - v + blockoff;
  rowptr[i] = excl;
  cursor[i] = excl;
  dinv[i] = rsqrtf((float)(v + 1));
  if (i == N_NODES - 1) rowptr[N_NODES] = excl + v;
}

// ---------- GEMM1 (blocks 0..1023, 16 rows/wave) + CSR fill (blocks 1024..1535) ----------
__global__ __launch_bounds__(256) void k_fill_gemm1(
    const int* __restrict__ src, const int* __restrict__ dst,
    int* __restrict__ cursor, int* __restrict__ csr_src, int e4,
    const float* __restrict__ x, const unsigned short* __restrict__ w1t,
    const float* __restrict__ dinv, unsigned short* __restrict__ xw1s) {
  if (blockIdx.x >= 1024) {
    // CSR fill: 8 edges per thread -> 8 independent atomic round-trips in flight
    int i = (blockIdx.x - 1024) * 256 + threadIdx.x;  // [0, 131072)
    int e8 = e4 >> 1;
    if (i < e8) {
      const int4* d4 = (const int4*)dst;
      const int4* s4 = (const int4*)src;
      int4 da = d4[2 * i], db = d4[2 * i + 1];
      int4 sa = s4[2 * i], sb = s4[2 * i + 1];
      int p0 = atomicAdd(&cursor[da.x], 1);
      int p1 = atomicAdd(&cursor[da.y], 1);
      int p2 = atomicAdd(&cursor[da.z], 1);
      int p3 = atomicAdd(&cursor[da.w], 1);
      int p4 = atomicAdd(&cursor[db.x], 1);
      int p5 = atomicAdd(&cursor[db.y], 1);
      int p6 = atomicAdd(&cursor[db.z], 1);
      int p7 = atomicAdd(&cursor[db.w], 1);
      csr_src[p0] = sa.x; csr_src[p1] = sa.y;
      csr_src[p2] = sa.z; csr_src[p3] = sa.w;
      csr_src[p4] = sb.x; csr_src[p5] = sb.y;
      csr_src[p6] = sb.z; csr_src[p7] = sb.w;
    }
    return;
  }
  int wave = threadIdx.x >> 6;
  int lane = threadIdx.x & 63;
  int quad = lane >> 4;
  int l16 = lane & 15;
  int rowbase = blockIdx.x * 64 + wave * 16;
  const float* xrow = x + (size_t)(rowbase + l16) * D_IN + quad * 8;
  const unsigned short* bbase = w1t + quad * 8;
  floatx4 acc[4];
#pragma unroll
  for (int nt = 0; nt < 4; nt++) acc[nt] = (floatx4){0.f, 0.f, 0.f, 0.f};
  // prefetch first 64-k chunk (4 independent HBM loads in flight)
  float4 p0 = *(const float4*)(xrow + 0);
  float4 p1 = *(const float4*)(xrow + 4);
  float4 p2 = *(const float4*)(xrow + 32);
  float4 p3 = *(const float4*)(xrow + 36);
  for (int k0 = 0; k0 < D_IN; k0 += 64) {
    float4 c0 = p0, c1 = p1, c2 = p2, c3 = p3;
    if (k0 + 64 < D_IN) {
      p0 = *(const float4*)(xrow + k0 + 64);
      p1 = *(const float4*)(xrow + k0 + 68);
      p2 = *(const float4*)(xrow + k0 + 96);
      p3 = *(const float4*)(xrow + k0 + 100);
    }
    float av0[8] = {c0.x, c0.y, c0.z, c0.w, c1.x, c1.y, c1.z, c1.w};
    float av1[8] = {c2.x, c2.y, c2.z, c2.w, c3.x, c3.y, c3.z, c3.w};
    // packed f32->bf16: 8 v_cvt_pk_bf16_f32 replaces ~64 VALU of manual rounding
    short8 af0, af1;
    unsigned* u0 = (unsigned*)&af0;
    unsigned* u1 = (unsigned*)&af1;
#pragma unroll
    for (int j = 0; j < 4; j++) {
      asm("v_cvt_pk_bf16_f32 %0, %1, %2" : "=v"(u0[j]) : "v"(av0[2 * j]), "v"(av0[2 * j + 1]));
      asm("v_cvt_pk_bf16_f32 %0, %1, %2" : "=v"(u1[j]) : "v"(av1[2 * j]), "v"(av1[2 * j + 1]));
    }
    short8 bf0[4], bf1[4];
#pragma unroll
    for (int nt = 0; nt < 4; nt++) {
      const unsigned short* bp = bbase + (size_t)(nt * 16 + l16) * D_IN + k0;
      bf0[nt] = *(const short8*)(bp);
      bf1[nt] = *(const short8*)(bp + 32);
    }
#pragma unroll
    for (int nt = 0; nt < 4; nt++)
      acc[nt] = __builtin_amdgcn_mfma_f32_16x16x32_bf16(af0, bf0[nt], acc[nt], 0, 0, 0);
#pragma unroll
    for (int nt = 0; nt < 4; nt++)
      acc[nt] = __builtin_amdgcn_mfma_f32_16x16x32_bf16(af1, bf1[nt], acc[nt], 0, 0, 0);
  }
#pragma unroll
  for (int r = 0; r < 4; r++) {
    int row = rowbase + quad * 4 + r;
    float sc = dinv[row];
#pragma unroll
    for (int nt = 0; nt < 4; nt++)
      xw1s[(size_t)row * D_HID + nt * 16 + l16] = f2bf(acc[nt][r] * sc);
  }
}

// ---------- agg1 + gemm2 fused; 16 predicated gather streams/wave, no tail ----------
__global__ __launch_bounds__(256) void k_agg1(const unsigned* __restrict__ xw1s2,
    const int* __restrict__ rowptr, const int* __restrict__ csr_src,
    const float* __restrict__ dinv, const float* __restrict__ b1,
    const float* __restrict__ w2, unsigned short* __restrict__ xw2s) {
  __shared__ float w2s[D_HID * N_CLS];
  for (int i = threadIdx.x; i < D_HID * N_CLS; i += 256) w2s[i] = w2[i];
  __syncthreads();
  int wave = threadIdx.x >> 6;
  int lane = threadIdx.x & 63;
  int h = lane >> 5, l = lane & 31;
  int node = blockIdx.x * 4 + wave;
  float dd = dinv[node];
  int beg = rowptr[node], end = rowptr[node + 1];
  float cx[8], cy[8];
#pragma unroll
  for (int j = 0; j < 8; j++) { cx[j] = 0.f; cy[j] = 0.f; }
  // predicated: every iteration keeps 16 gathers (8 per half-wave) in flight
  for (int e = beg + h; e < end; e += 16) {
    int idx[8]; bool val[8];
#pragma unroll
    for (int j = 0; j < 8; j++) {
      int ee = e + 2 * j;
      val[j] = ee < end;
      idx[j] = csr_src[val[j] ? ee : beg];
    }
#pragma unroll
    for (int j = 0; j < 8; j++) {
      float2 v = bf2f2(xw1s2[(size_t)idx[j] * 32 + l]);
      cx[j] += val[j] ? v.x : 0.f;
      cy[j] += val[j] ? v.y : 0.f;
    }
  }
  float sx = ((cx[0] + cx[1]) + (cx[2] + cx[3])) + ((cx[4] + cx[5]) + (cx[6] + cx[7]));
  float sy = ((cy[0] + cy[1]) + (cy[2] + cy[3])) + ((cy[4] + cy[5]) + (cy[6] + cy[7]));
  sx += __shfl_xor(sx, 32);
  sy += __shfl_xor(sy, 32);
  // all lanes: self contribution + bias + relu (lanes 32-63 mirror 0-31)
  float2 self = bf2f2(xw1s2[(size_t)node * 32 + l]);
  float2 bb = ((const float2*)b1)[l];
  float vx = dd * (sx + self.x) + bb.x;
  float vy = dd * (sy + self.y) + bb.y;
  vx = vx > 0.f ? vx : 0.f;
  vy = vy > 0.f ? vy : 0.f;
  // GEMM2 via shfl broadcast: lane (h,c) accumulates k = h*32..h*32+31
  int c = lane & 31;
  float p = 0.f;
#pragma unroll
  for (int kk = 0; kk < 32; kk++) {
    int k = h * 32 + kk;
    float hv = (k & 1) ? __shfl(vy, k >> 1) : __shfl(vx, k >> 1);
    p += hv * w2s[k * N_CLS + c];
  }
  p += __shfl_xor(p, 32);
  if (lane < 32) xw2s[(size_t)node * N_CLS + c] = f2bf(p * dd);
}

// ---------- agg2 + log_softmax; 16 predicated gather streams/wave, no tail ----------
__global__ __launch_bounds__(256) void k_agg2(const unsigned* __restrict__ xw2s2,
    const int* __restrict__ rowptr, const int* __restrict__ csr_src,
    const float* __restrict__ dinv, const float* __restrict__ b2,
    float* __restrict__ out) {
  int wave = threadIdx.x >> 6;
  int lane = threadIdx.x & 63;
  int q = lane >> 4, l = lane & 15;
  int node = blockIdx.x * 4 + wave;
  float dd = dinv[node];
  int beg = rowptr[node], end = rowptr[node + 1];
  float cx[4], cy[4];
#pragma unroll
  for (int j = 0; j < 4; j++) { cx[j] = 0.f; cy[j] = 0.f; }
  for (int e = beg + q; e < end; e += 16) {
    int idx[4]; bool val[4];
#pragma unroll
    for (int j = 0; j < 4; j++) {
      int ee = e + 4 * j;
      val[j] = ee < end;
      idx[j] = csr_src[val[j] ? ee : beg];
    }
#pragma unroll
    for (int j = 0; j < 4; j++) {
      float2 v = bf2f2(xw2s2[(size_t)idx[j] * 16 + l]);
      cx[j] += val[j] ? v.x : 0.f;
      cy[j] += val[j] ? v.y : 0.f;
    }
  }
  float sx = (cx[0] + cx[1]) + (cx[2] + cx[3]);
  float sy = (cy[0] + cy[1]) + (cy[2] + cy[3]);
  sx += __shfl_xor(sx, 32); sy += __shfl_xor(sy, 32);
  sx += __shfl_xor(sx, 16); sy += __shfl_xor(sy, 16);
  // all lanes now hold the full sums for column pair (2l, 2l+1)
  float2 self = bf2f2(xw2s2[(size_t)node * 16 + l]);
  float2 bb = ((const float2*)b2)[l];
  float lx = dd * (sx + self.x) + bb.x;
  float ly = dd * (sy + self.y) + bb.y;
  float m = fmaxf(lx, ly);
#pragma unroll
  for (int o = 8; o > 0; o >>= 1) m = fmaxf(m, __shfl_xor(m, o));
  float s2 = __expf(lx - m) + __expf(ly - m);
#pragma unroll
  for (int o = 8; o > 0; o >>= 1) s2 += __shfl_xor(s2, o);
  float lse = m + __logf(s2);
  if (lane < 16)
    ((float2*)out)[(size_t)node * 16 + l] = make_float2(lx - lse, ly - lse);
}

extern "C" void kernel_launch(void* const* d_in, const int* in_sizes, int n_in,
                              void* d_out, int out_size, void* d_ws, size_t ws_size,
                              hipStream_t stream) {
  (void)n_in; (void)out_size; (void)ws_size;
  const float* x  = (const float*)d_in[0];
  const int*   ei = (const int*)d_in[1];
  const float* w1 = (const float*)d_in[2];
  const float* b1 = (const float*)d_in[3];
  const float* w2 = (const float*)d_in[4];
  const float* b2 = (const float*)d_in[5];
  float* out = (float*)d_out;
  int e = in_sizes[1] / 2;
  const int* src = ei;
  const int* dst = ei + e;

  char* ws = (char*)d_ws;
  int* cnt            = (int*)(ws + 0x000000);            // 256KB
  int* rowptr         = (int*)(ws + 0x040000);            // 256KB + 4
  int* cursor         = (int*)(ws + 0x0C0000);            // 256KB
  float* dinv         = (float*)(ws + 0x100000);          // 256KB
  int* bsum           = (int*)(ws + 0x140000);            // 1KB
  int* csr_src        = (int*)(ws + 0x180000);            // 4MB
  unsigned short* w1t = (unsigned short*)(ws + 0x580000); // 128KB
  unsigned short* xw1s= (unsigned short*)(ws + 0x600000); // 8MB (bf16)
  unsigned short* xw2s= (unsigned short*)(ws + 0xE00000); // 4MB (bf16)

  int e4 = e / 4;
  hipMemsetAsync(cnt, 0, N_NODES * sizeof(int), stream);
  k_count_w1t<<<1280, 256, 0, stream>>>(dst, cnt, w1, w1t, e4);
  k_scan_a   <<<N_NODES / 256, 256, 0, stream>>>(cnt, bsum);
  k_scan_c   <<<N_NODES / 256, 256, 0, stream>>>(cnt, bsum, rowptr, cursor, dinv);
  k_fill_gemm1<<<1536, 256, 0, stream>>>(src, dst, cursor, csr_src, e4,
                                         x, w1t, dinv, xw1s);
  k_agg1     <<<N_NODES / 4, 256, 0, stream>>>((const unsigned*)xw1s, rowptr, csr_src,
                                               dinv, b1, w2, xw2s);
  k_agg2     <<<N_NODES / 4, 256, 0, stream>>>((const unsigned*)xw2s, rowptr, csr_src,
                                               dinv, b2, out);
}

// Round 2
// 549.077 us; speedup vs baseline: 1.0274x; 1.0072x over previous
//
#include <hip/hip_runtime.h>
#include <hip/hip_bf16.h>

#define N_NODES 65536
#define D_IN 1024
#define D_HID 64
#define N_CLS 32
// one counter per 128B cache line: kills cross-XCD same-line atomic ping-pong
#define CPAD 5  // stride 32 ints = 128 B

typedef short short8 __attribute__((ext_vector_type(8)));
typedef float floatx4 __attribute__((ext_vector_type(4)));

// ---------- helpers ----------
__device__ __forceinline__ unsigned short f2bf(float f) {
  union { float f; unsigned u; } cv; cv.f = f;
  unsigned r = (cv.u + 0x7FFFu + ((cv.u >> 16) & 1u)) >> 16;
  return (unsigned short)r;
}
__device__ __forceinline__ float2 bf2f2(unsigned v) {
  union { unsigned u; float f; } a, b;
  a.u = v << 16;
  b.u = v & 0xFFFF0000u;
  return make_float2(a.f, b.f);  // (elem 2l, elem 2l+1)
}

// ---------- count (blocks 0..1023) + W1 transpose->bf16 (blocks 1024..1279) ----------
__global__ void k_count_w1t(const int* __restrict__ dst, int* __restrict__ cnt,
                            const float* __restrict__ w1, unsigned short* __restrict__ w1t,
                            int e4) {
  int b = blockIdx.x;
  if (b >= 1024) {
    int i = (b - 1024) * 256 + threadIdx.x;  // [0, 65536)
    int k = i / D_HID, n = i % D_HID;
    w1t[n * D_IN + k] = f2bf(w1[i]);
    return;
  }
  int i = b * 256 + threadIdx.x;
  if (i < e4) {
    int4 d = ((const int4*)dst)[i];
    atomicAdd(&cnt[d.x << CPAD], 1);
    atomicAdd(&cnt[d.y << CPAD], 1);
    atomicAdd(&cnt[d.z << CPAD], 1);
    atomicAdd(&cnt[d.w << CPAD], 1);
  }
}

// ---------- scan phase A: per-block sums (padded cnt) ----------
__global__ void k_scan_a(const int* __restrict__ cnt, int* __restrict__ bsum) {
  __shared__ int s[256];
  int t = threadIdx.x;
  s[t] = cnt[(blockIdx.x * 256 + t) << CPAD];
  __syncthreads();
  for (int off = 128; off > 0; off >>= 1) {
    if (t < off) s[t] += s[t + off];
    __syncthreads();
  }
  if (t == 0) bsum[blockIdx.x] = s[0];
}

// ---------- scan phase C: block-offset reduce + rowptr/cursor/dinv (padded) ----------
__global__ void k_scan_c(const int* __restrict__ cnt, const int* __restrict__ bsum,
                         int* __restrict__ rowptr, int* __restrict__ cursor,
                         float* __restrict__ dinv) {
  __shared__ int s[256];
  int t = threadIdx.x;
  s[t] = (t < blockIdx.x) ? bsum[t] : 0;
  __syncthreads();
  for (int off = 128; off > 0; off >>= 1) {
    if (t < off) s[t] += s[t + off];
    __syncthreads();
  }
  int blockoff = s[0];
  __syncthreads();
  int i = blockIdx.x * 256 + t;
  int v = cnt[i << CPAD];
  s[t] = v;
  __syncthreads();
  for (int off = 1; off < 256; off <<= 1) {
    int x = (t >= off) ? s[t - off] : 0;
    __syncthreads();
    s[t] += x;
    __syncthreads();
  }
  int excl = s[t] - v + blockoff;
  rowptr[i] = excl;
  cursor[i << CPAD] = excl;
  dinv[i] = rsqrtf((float)(v + 1));
  if (i == N_NODES - 1) rowptr[N_NODES] = excl + v;
}

// ---------- GEMM1 (blocks 0..1023, 16 rows/wave) + CSR fill (blocks 1024..1535) ----------
__global__ __launch_bounds__(256) void k_fill_gemm1(
    const int* __restrict__ src, const int* __restrict__ dst,
    int* __restrict__ cursor, int* __restrict__ csr_src, int e4,
    const float* __restrict__ x, const unsigned short* __restrict__ w1t,
    const float* __restrict__ dinv, unsigned short* __restrict__ xw1s) {
  if (blockIdx.x >= 1024) {
    // CSR fill: 8 edges per thread, 8 independent atomic round-trips in flight
    int i = (blockIdx.x - 1024) * 256 + threadIdx.x;  // [0, 131072)
    int e8 = e4 >> 1;
    if (i < e8) {
      const int4* d4 = (const int4*)dst;
      const int4* s4 = (const int4*)src;
      int4 da = d4[2 * i], db = d4[2 * i + 1];
      int4 sa = s4[2 * i], sb = s4[2 * i + 1];
      int p0 = atomicAdd(&cursor[da.x << CPAD], 1);
      int p1 = atomicAdd(&cursor[da.y << CPAD], 1);
      int p2 = atomicAdd(&cursor[da.z << CPAD], 1);
      int p3 = atomicAdd(&cursor[da.w << CPAD], 1);
      int p4 = atomicAdd(&cursor[db.x << CPAD], 1);
      int p5 = atomicAdd(&cursor[db.y << CPAD], 1);
      int p6 = atomicAdd(&cursor[db.z << CPAD], 1);
      int p7 = atomicAdd(&cursor[db.w << CPAD], 1);
      csr_src[p0] = sa.x; csr_src[p1] = sa.y;
      csr_src[p2] = sa.z; csr_src[p3] = sa.w;
      csr_src[p4] = sb.x; csr_src[p5] = sb.y;
      csr_src[p6] = sb.z; csr_src[p7] = sb.w;
    }
    return;
  }
  int wave = threadIdx.x >> 6;
  int lane = threadIdx.x & 63;
  int quad = lane >> 4;
  int l16 = lane & 15;
  int rowbase = blockIdx.x * 64 + wave * 16;
  const float* xrow = x + (size_t)(rowbase + l16) * D_IN + quad * 8;
  const unsigned short* bbase = w1t + quad * 8;
  floatx4 acc[4];
#pragma unroll
  for (int nt = 0; nt < 4; nt++) acc[nt] = (floatx4){0.f, 0.f, 0.f, 0.f};
  // prefetch slice 0: A (4 HBM/L3 loads) + B (8 L2 loads)
  float4 p0 = *(const float4*)(xrow + 0);
  float4 p1 = *(const float4*)(xrow + 4);
  float4 p2 = *(const float4*)(xrow + 32);
  float4 p3 = *(const float4*)(xrow + 36);
  short8 bf0[4], bf1[4];
#pragma unroll
  for (int nt = 0; nt < 4; nt++) {
    const unsigned short* bp = bbase + (size_t)(nt * 16 + l16) * D_IN;
    bf0[nt] = *(const short8*)(bp);
    bf1[nt] = *(const short8*)(bp + 32);
  }
  for (int k0 = 0; k0 < D_IN; k0 += 64) {
    float4 c0 = p0, c1 = p1, c2 = p2, c3 = p3;
    int kn = (k0 + 64 < D_IN) ? k0 + 64 : k0;  // clamped (last reload is dead)
    p0 = *(const float4*)(xrow + kn);
    p1 = *(const float4*)(xrow + kn + 4);
    p2 = *(const float4*)(xrow + kn + 32);
    p3 = *(const float4*)(xrow + kn + 36);
    float av0[8] = {c0.x, c0.y, c0.z, c0.w, c1.x, c1.y, c1.z, c1.w};
    float av1[8] = {c2.x, c2.y, c2.z, c2.w, c3.x, c3.y, c3.z, c3.w};
    short8 af0, af1;
    unsigned* u0 = (unsigned*)&af0;
    unsigned* u1 = (unsigned*)&af1;
#pragma unroll
    for (int j = 0; j < 4; j++) {
      asm("v_cvt_pk_bf16_f32 %0, %1, %2" : "=v"(u0[j]) : "v"(av0[2 * j]), "v"(av0[2 * j + 1]));
      asm("v_cvt_pk_bf16_f32 %0, %1, %2" : "=v"(u1[j]) : "v"(av1[2 * j]), "v"(av1[2 * j + 1]));
    }
    // consume bf0, then reload in place with next slice (in-flight across rest of iter)
#pragma unroll
    for (int nt = 0; nt < 4; nt++)
      acc[nt] = __builtin_amdgcn_mfma_f32_16x16x32_bf16(af0, bf0[nt], acc[nt], 0, 0, 0);
#pragma unroll
    for (int nt = 0; nt < 4; nt++)
      bf0[nt] = *(const short8*)(bbase + (size_t)(nt * 16 + l16) * D_IN + kn);
#pragma unroll
    for (int nt = 0; nt < 4; nt++)
      acc[nt] = __builtin_amdgcn_mfma_f32_16x16x32_bf16(af1, bf1[nt], acc[nt], 0, 0, 0);
#pragma unroll
    for (int nt = 0; nt < 4; nt++)
      bf1[nt] = *(const short8*)(bbase + (size_t)(nt * 16 + l16) * D_IN + kn + 32);
  }
#pragma unroll
  for (int r = 0; r < 4; r++) {
    int row = rowbase + quad * 4 + r;
    float sc = dinv[row];
#pragma unroll
    for (int nt = 0; nt < 4; nt++)
      xw1s[(size_t)row * D_HID + nt * 16 + l16] = f2bf(acc[nt][r] * sc);
  }
}

// ---------- agg1 + gemm2 fused; 16 predicated gather streams/wave ----------
__global__ __launch_bounds__(256) void k_agg1(const unsigned* __restrict__ xw1s2,
    const int* __restrict__ rowptr, const int* __restrict__ csr_src,
    const float* __restrict__ dinv, const float* __restrict__ b1,
    const float* __restrict__ w2, unsigned short* __restrict__ xw2s) {
  __shared__ float w2s[D_HID * N_CLS];
  for (int i = threadIdx.x; i < D_HID * N_CLS; i += 256) w2s[i] = w2[i];
  __syncthreads();
  int wave = threadIdx.x >> 6;
  int lane = threadIdx.x & 63;
  int h = lane >> 5, l = lane & 31;
  int node = blockIdx.x * 4 + wave;
  float dd = dinv[node];
  int beg = rowptr[node], end = rowptr[node + 1];
  float cx[8], cy[8];
#pragma unroll
  for (int j = 0; j < 8; j++) { cx[j] = 0.f; cy[j] = 0.f; }
  for (int e = beg + h; e < end; e += 16) {
    int idx[8]; bool val[8];
#pragma unroll
    for (int j = 0; j < 8; j++) {
      int ee = e + 2 * j;
      val[j] = ee < end;
      idx[j] = csr_src[val[j] ? ee : beg];
    }
#pragma unroll
    for (int j = 0; j < 8; j++) {
      float2 v = bf2f2(xw1s2[(size_t)idx[j] * 32 + l]);
      cx[j] += val[j] ? v.x : 0.f;
      cy[j] += val[j] ? v.y : 0.f;
    }
  }
  float sx = ((cx[0] + cx[1]) + (cx[2] + cx[3])) + ((cx[4] + cx[5]) + (cx[6] + cx[7]));
  float sy = ((cy[0] + cy[1]) + (cy[2] + cy[3])) + ((cy[4] + cy[5]) + (cy[6] + cy[7]));
  sx += __shfl_xor(sx, 32);
  sy += __shfl_xor(sy, 32);
  float2 self = bf2f2(xw1s2[(size_t)node * 32 + l]);
  float2 bb = ((const float2*)b1)[l];
  float vx = dd * (sx + self.x) + bb.x;
  float vy = dd * (sy + self.y) + bb.y;
  vx = vx > 0.f ? vx : 0.f;
  vy = vy > 0.f ? vy : 0.f;
  int c = lane & 31;
  float p = 0.f;
#pragma unroll
  for (int kk = 0; kk < 32; kk++) {
    int k = h * 32 + kk;
    float hv = (k & 1) ? __shfl(vy, k >> 1) : __shfl(vx, k >> 1);
    p += hv * w2s[k * N_CLS + c];
  }
  p += __shfl_xor(p, 32);
  if (lane < 32) xw2s[(size_t)node * N_CLS + c] = f2bf(p * dd);
}

// ---------- agg2 + log_softmax; 16 predicated gather streams/wave ----------
__global__ __launch_bounds__(256) void k_agg2(const unsigned* __restrict__ xw2s2,
    const int* __restrict__ rowptr, const int* __restrict__ csr_src,
    const float* __restrict__ dinv, const float* __restrict__ b2,
    float* __restrict__ out) {
  int wave = threadIdx.x >> 6;
  int lane = threadIdx.x & 63;
  int q = lane >> 4, l = lane & 15;
  int node = blockIdx.x * 4 + wave;
  float dd = dinv[node];
  int beg = rowptr[node], end = rowptr[node + 1];
  float cx[4], cy[4];
#pragma unroll
  for (int j = 0; j < 4; j++) { cx[j] = 0.f; cy[j] = 0.f; }
  for (int e = beg + q; e < end; e += 16) {
    int idx[4]; bool val[4];
#pragma unroll
    for (int j = 0; j < 4; j++) {
      int ee = e + 4 * j;
      val[j] = ee < end;
      idx[j] = csr_src[val[j] ? ee : beg];
    }
#pragma unroll
    for (int j = 0; j < 4; j++) {
      float2 v = bf2f2(xw2s2[(size_t)idx[j] * 16 + l]);
      cx[j] += val[j] ? v.x : 0.f;
      cy[j] += val[j] ? v.y : 0.f;
    }
  }
  float sx = (cx[0] + cx[1]) + (cx[2] + cx[3]);
  float sy = (cy[0] + cy[1]) + (cy[2] + cy[3]);
  sx += __shfl_xor(sx, 32); sy += __shfl_xor(sy, 32);
  sx += __shfl_xor(sx, 16); sy += __shfl_xor(sy, 16);
  float2 self = bf2f2(xw2s2[(size_t)node * 16 + l]);
  float2 bb = ((const float2*)b2)[l];
  float lx = dd * (sx + self.x) + bb.x;
  float ly = dd * (sy + self.y) + bb.y;
  float m = fmaxf(lx, ly);
#pragma unroll
  for (int o = 8; o > 0; o >>= 1) m = fmaxf(m, __shfl_xor(m, o));
  float s2 = __expf(lx - m) + __expf(ly - m);
#pragma unroll
  for (int o = 8; o > 0; o >>= 1) s2 += __shfl_xor(s2, o);
  float lse = m + __logf(s2);
  if (lane < 16)
    ((float2*)out)[(size_t)node * 16 + l] = make_float2(lx - lse, ly - lse);
}

extern "C" void kernel_launch(void* const* d_in, const int* in_sizes, int n_in,
                              void* d_out, int out_size, void* d_ws, size_t ws_size,
                              hipStream_t stream) {
  (void)n_in; (void)out_size; (void)ws_size;
  const float* x  = (const float*)d_in[0];
  const int*   ei = (const int*)d_in[1];
  const float* w1 = (const float*)d_in[2];
  const float* b1 = (const float*)d_in[3];
  const float* w2 = (const float*)d_in[4];
  const float* b2 = (const float*)d_in[5];
  float* out = (float*)d_out;
  int e = in_sizes[1] / 2;
  const int* src = ei;
  const int* dst = ei + e;

  char* ws = (char*)d_ws;
  int* cnt            = (int*)(ws + 0x0000000);           // 8MB (padded, 128B/counter)
  int* cursor         = (int*)(ws + 0x0800000);           // 8MB (padded)
  int* rowptr         = (int*)(ws + 0x1000000);           // 256KB + 4
  float* dinv         = (float*)(ws + 0x1050000);         // 256KB
  int* bsum           = (int*)(ws + 0x1090000);           // 1KB
  int* csr_src        = (int*)(ws + 0x10A0000);           // 4MB
  unsigned short* w1t = (unsigned short*)(ws + 0x14A0000);// 128KB
  unsigned short* xw1s= (unsigned short*)(ws + 0x14C0000);// 8MB (bf16)
  unsigned short* xw2s= (unsigned short*)(ws + 0x1CC0000);// 4MB (bf16)

  int e4 = e / 4;
  hipMemsetAsync(cnt, 0, (size_t)N_NODES * 32 * sizeof(int), stream);
  k_count_w1t<<<1280, 256, 0, stream>>>(dst, cnt, w1, w1t, e4);
  k_scan_a   <<<N_NODES / 256, 256, 0, stream>>>(cnt, bsum);
  k_scan_c   <<<N_NODES / 256, 256, 0, stream>>>(cnt, bsum, rowptr, cursor, dinv);
  k_fill_gemm1<<<1536, 256, 0, stream>>>(src, dst, cursor, csr_src, e4,
                                         x, w1t, dinv, xw1s);
  k_agg1     <<<N_NODES / 4, 256, 0, stream>>>((const unsigned*)xw1s, rowptr, csr_src,
                                               dinv, b1, w2, xw2s);
  k_agg2     <<<N_NODES / 4, 256, 0, stream>>>((const unsigned*)xw2s, rowptr, csr_src,
                                               dinv, b2, out);
}

// Round 3
// 493.859 us; speedup vs baseline: 1.1423x; 1.1118x over previous
//
#include <hip/hip_runtime.h>
#include <hip/hip_bf16.h>

#define N_NODES 65536
#define D_IN 1024
#define D_HID 64
#define N_CLS 32
#define NBUK 256   // buckets keyed by dst >> 8
#define NEB 1024   // edge-blocks in hist/scatter (1024 edges each)

typedef short short8 __attribute__((ext_vector_type(8)));
typedef float floatx4 __attribute__((ext_vector_type(4)));

// ---------- helpers ----------
__device__ __forceinline__ unsigned short f2bf(float f) {
  union { float f; unsigned u; } cv; cv.f = f;
  unsigned r = (cv.u + 0x7FFFu + ((cv.u >> 16) & 1u)) >> 16;
  return (unsigned short)r;
}
__device__ __forceinline__ float2 bf2f2(unsigned v) {
  union { unsigned u; float f; } a, b;
  a.u = v << 16;
  b.u = v & 0xFFFF0000u;
  return make_float2(a.f, b.f);  // (elem 2l, elem 2l+1)
}

// ---------- pass 1: LDS histogram by dst>>8 (blocks 0..1023) + W1^T->bf16 ----------
__global__ void k_hist(const int* __restrict__ dst, int* __restrict__ H,
                       const float* __restrict__ w1, unsigned short* __restrict__ w1t,
                       int e4) {
  int b = blockIdx.x;
  if (b >= NEB) {
    int i = (b - NEB) * 256 + threadIdx.x;  // [0, 65536)
    int k = i / D_HID, n = i % D_HID;
    w1t[n * D_IN + k] = f2bf(w1[i]);
    return;
  }
  __shared__ int hist[NBUK];
  int t = threadIdx.x;
  hist[t] = 0;
  __syncthreads();
  int i4 = b * 256 + t;
  if (i4 < e4) {
    int4 d = ((const int4*)dst)[i4];
    atomicAdd(&hist[d.x >> 8], 1);
    atomicAdd(&hist[d.y >> 8], 1);
    atomicAdd(&hist[d.z >> 8], 1);
    atomicAdd(&hist[d.w >> 8], 1);
  }
  __syncthreads();
  H[t * NEB + b] = hist[t];  // bin-major
}

// ---------- pass 2a: per-bucket exclusive scan of 1024 block-counts ----------
__global__ void k_scan_bucket(int* __restrict__ H, int* __restrict__ btot) {
  int bin = blockIdx.x, t = threadIdx.x;
  int4 v = ((int4*)(H + bin * NEB))[t];
  int s0 = v.x, s1 = s0 + v.y, s2 = s1 + v.z, s3 = s2 + v.w;
  __shared__ int s[256];
  s[t] = s3;
  __syncthreads();
  for (int off = 1; off < 256; off <<= 1) {
    int x = (t >= off) ? s[t - off] : 0;
    __syncthreads();
    s[t] += x;
    __syncthreads();
  }
  int excl = s[t] - s3;
  ((int4*)(H + bin * NEB))[t] = make_int4(excl, excl + s0, excl + s1, excl + s2);
  if (t == 255) btot[bin] = excl + s3;
}

// ---------- pass 2b: scan bucket totals -> bucket base offsets ----------
__global__ void k_scan_tot(const int* __restrict__ btot, int* __restrict__ btoff,
                           int* __restrict__ rowptr, int e) {
  __shared__ int s[256];
  int t = threadIdx.x;
  int v = btot[t];
  s[t] = v;
  __syncthreads();
  for (int off = 1; off < 256; off <<= 1) {
    int x = (t >= off) ? s[t - off] : 0;
    __syncthreads();
    s[t] += x;
    __syncthreads();
  }
  btoff[t] = s[t] - v;
  if (t == 0) rowptr[N_NODES] = e;
}

// ---------- pass 3: bucket-sorted scatter of packed (dst_low8, src) ----------
__global__ void k_scatter(const int* __restrict__ dst, const int* __restrict__ src,
                          const int* __restrict__ H, const int* __restrict__ btoff,
                          unsigned* __restrict__ pk, int e4) {
  __shared__ int cur[NBUK];
  int b = blockIdx.x, t = threadIdx.x;
  cur[t] = btoff[t] + H[t * NEB + b];  // this block's exclusive window per bucket
  __syncthreads();
  int i4 = b * 256 + t;
  if (i4 < e4) {
    int4 d = ((const int4*)dst)[i4];
    int4 sv = ((const int4*)src)[i4];
    int p0 = atomicAdd(&cur[d.x >> 8], 1);
    int p1 = atomicAdd(&cur[d.y >> 8], 1);
    int p2 = atomicAdd(&cur[d.z >> 8], 1);
    int p3 = atomicAdd(&cur[d.w >> 8], 1);
    pk[p0] = ((unsigned)(d.x & 255) << 16) | (unsigned)sv.x;
    pk[p1] = ((unsigned)(d.y & 255) << 16) | (unsigned)sv.y;
    pk[p2] = ((unsigned)(d.z & 255) << 16) | (unsigned)sv.z;
    pk[p3] = ((unsigned)(d.w & 255) << 16) | (unsigned)sv.w;
  }
}

// ---------- pass 4: per-bucket local CSR (rowptr, dinv, csr_src) ----------
__global__ void k_bucket_csr(const unsigned* __restrict__ pk, const int* __restrict__ btoff,
                             const int* __restrict__ btot, int* __restrict__ rowptr,
                             int* __restrict__ csr_src, float* __restrict__ dinv) {
  __shared__ int cnt[NBUK], sc[NBUK], cur[NBUK];
  int bin = blockIdx.x, t = threadIdx.x;
  cnt[t] = 0;
  __syncthreads();
  int beg = btoff[bin], len = btot[bin];
  for (int i = t; i < len; i += 256)
    atomicAdd(&cnt[(pk[beg + i] >> 16) & 255], 1);
  __syncthreads();
  int c = cnt[t];
  sc[t] = c;
  __syncthreads();
  for (int off = 1; off < 256; off <<= 1) {
    int x = (t >= off) ? sc[t - off] : 0;
    __syncthreads();
    sc[t] += x;
    __syncthreads();
  }
  int excl = sc[t] - c;
  int node = bin * 256 + t;
  rowptr[node] = beg + excl;
  dinv[node] = rsqrtf((float)(c + 1));
  cur[t] = excl;
  __syncthreads();
  for (int i = t; i < len; i += 256) {
    unsigned u = pk[beg + i];
    int p = atomicAdd(&cur[(u >> 16) & 255], 1);
    csr_src[beg + p] = (int)(u & 0xFFFFu);
  }
}

// ---------- GEMM1: xw1s = (x @ W1) * dinv, bf16 out; 16 rows/wave ----------
__global__ __launch_bounds__(256) void k_gemm1(
    const float* __restrict__ x, const unsigned short* __restrict__ w1t,
    const float* __restrict__ dinv, unsigned short* __restrict__ xw1s) {
  int wave = threadIdx.x >> 6;
  int lane = threadIdx.x & 63;
  int quad = lane >> 4;
  int l16 = lane & 15;
  int rowbase = blockIdx.x * 64 + wave * 16;
  const float* xrow = x + (size_t)(rowbase + l16) * D_IN + quad * 8;
  const unsigned short* bbase = w1t + quad * 8;
  floatx4 acc[4];
#pragma unroll
  for (int nt = 0; nt < 4; nt++) acc[nt] = (floatx4){0.f, 0.f, 0.f, 0.f};
  float4 p0 = *(const float4*)(xrow + 0);
  float4 p1 = *(const float4*)(xrow + 4);
  float4 p2 = *(const float4*)(xrow + 32);
  float4 p3 = *(const float4*)(xrow + 36);
  short8 bf0[4], bf1[4];
#pragma unroll
  for (int nt = 0; nt < 4; nt++) {
    const unsigned short* bp = bbase + (size_t)(nt * 16 + l16) * D_IN;
    bf0[nt] = *(const short8*)(bp);
    bf1[nt] = *(const short8*)(bp + 32);
  }
  for (int k0 = 0; k0 < D_IN; k0 += 64) {
    float4 c0 = p0, c1 = p1, c2 = p2, c3 = p3;
    int kn = (k0 + 64 < D_IN) ? k0 + 64 : k0;
    p0 = *(const float4*)(xrow + kn);
    p1 = *(const float4*)(xrow + kn + 4);
    p2 = *(const float4*)(xrow + kn + 32);
    p3 = *(const float4*)(xrow + kn + 36);
    float av0[8] = {c0.x, c0.y, c0.z, c0.w, c1.x, c1.y, c1.z, c1.w};
    float av1[8] = {c2.x, c2.y, c2.z, c2.w, c3.x, c3.y, c3.z, c3.w};
    short8 af0, af1;
    unsigned* u0 = (unsigned*)&af0;
    unsigned* u1 = (unsigned*)&af1;
#pragma unroll
    for (int j = 0; j < 4; j++) {
      asm("v_cvt_pk_bf16_f32 %0, %1, %2" : "=v"(u0[j]) : "v"(av0[2 * j]), "v"(av0[2 * j + 1]));
      asm("v_cvt_pk_bf16_f32 %0, %1, %2" : "=v"(u1[j]) : "v"(av1[2 * j]), "v"(av1[2 * j + 1]));
    }
#pragma unroll
    for (int nt = 0; nt < 4; nt++)
      acc[nt] = __builtin_amdgcn_mfma_f32_16x16x32_bf16(af0, bf0[nt], acc[nt], 0, 0, 0);
#pragma unroll
    for (int nt = 0; nt < 4; nt++)
      bf0[nt] = *(const short8*)(bbase + (size_t)(nt * 16 + l16) * D_IN + kn);
#pragma unroll
    for (int nt = 0; nt < 4; nt++)
      acc[nt] = __builtin_amdgcn_mfma_f32_16x16x32_bf16(af1, bf1[nt], acc[nt], 0, 0, 0);
#pragma unroll
    for (int nt = 0; nt < 4; nt++)
      bf1[nt] = *(const short8*)(bbase + (size_t)(nt * 16 + l16) * D_IN + kn + 32);
  }
#pragma unroll
  for (int r = 0; r < 4; r++) {
    int row = rowbase + quad * 4 + r;
    float sc = dinv[row];
#pragma unroll
    for (int nt = 0; nt < 4; nt++)
      xw1s[(size_t)row * D_HID + nt * 16 + l16] = f2bf(acc[nt][r] * sc);
  }
}

// ---------- agg1 + gemm2 fused; 16 predicated gather streams/wave ----------
__global__ __launch_bounds__(256) void k_agg1(const unsigned* __restrict__ xw1s2,
    const int* __restrict__ rowptr, const int* __restrict__ csr_src,
    const float* __restrict__ dinv, const float* __restrict__ b1,
    const float* __restrict__ w2, unsigned short* __restrict__ xw2s) {
  __shared__ float w2s[D_HID * N_CLS];
  for (int i = threadIdx.x; i < D_HID * N_CLS; i += 256) w2s[i] = w2[i];
  __syncthreads();
  int wave = threadIdx.x >> 6;
  int lane = threadIdx.x & 63;
  int h = lane >> 5, l = lane & 31;
  int node = blockIdx.x * 4 + wave;
  float dd = dinv[node];
  int beg = rowptr[node], end = rowptr[node + 1];
  float cx[8], cy[8];
#pragma unroll
  for (int j = 0; j < 8; j++) { cx[j] = 0.f; cy[j] = 0.f; }
  for (int e = beg + h; e < end; e += 16) {
    int idx[8]; bool val[8];
#pragma unroll
    for (int j = 0; j < 8; j++) {
      int ee = e + 2 * j;
      val[j] = ee < end;
      idx[j] = csr_src[val[j] ? ee : beg];
    }
#pragma unroll
    for (int j = 0; j < 8; j++) {
      float2 v = bf2f2(xw1s2[(size_t)idx[j] * 32 + l]);
      cx[j] += val[j] ? v.x : 0.f;
      cy[j] += val[j] ? v.y : 0.f;
    }
  }
  float sx = ((cx[0] + cx[1]) + (cx[2] + cx[3])) + ((cx[4] + cx[5]) + (cx[6] + cx[7]));
  float sy = ((cy[0] + cy[1]) + (cy[2] + cy[3])) + ((cy[4] + cy[5]) + (cy[6] + cy[7]));
  sx += __shfl_xor(sx, 32);
  sy += __shfl_xor(sy, 32);
  float2 self = bf2f2(xw1s2[(size_t)node * 32 + l]);
  float2 bb = ((const float2*)b1)[l];
  float vx = dd * (sx + self.x) + bb.x;
  float vy = dd * (sy + self.y) + bb.y;
  vx = vx > 0.f ? vx : 0.f;
  vy = vy > 0.f ? vy : 0.f;
  int c = lane & 31;
  float p = 0.f;
#pragma unroll
  for (int kk = 0; kk < 32; kk++) {
    int k = h * 32 + kk;
    float hv = (k & 1) ? __shfl(vy, k >> 1) : __shfl(vx, k >> 1);
    p += hv * w2s[k * N_CLS + c];
  }
  p += __shfl_xor(p, 32);
  if (lane < 32) xw2s[(size_t)node * N_CLS + c] = f2bf(p * dd);
}

// ---------- agg2 + log_softmax; 16 predicated gather streams/wave ----------
__global__ __launch_bounds__(256) void k_agg2(const unsigned* __restrict__ xw2s2,
    const int* __restrict__ rowptr, const int* __restrict__ csr_src,
    const float* __restrict__ dinv, const float* __restrict__ b2,
    float* __restrict__ out) {
  int wave = threadIdx.x >> 6;
  int lane = threadIdx.x & 63;
  int q = lane >> 4, l = lane & 15;
  int node = blockIdx.x * 4 + wave;
  float dd = dinv[node];
  int beg = rowptr[node], end = rowptr[node + 1];
  float cx[4], cy[4];
#pragma unroll
  for (int j = 0; j < 4; j++) { cx[j] = 0.f; cy[j] = 0.f; }
  for (int e = beg + q; e < end; e += 16) {
    int idx[4]; bool val[4];
#pragma unroll
    for (int j = 0; j < 4; j++) {
      int ee = e + 4 * j;
      val[j] = ee < end;
      idx[j] = csr_src[val[j] ? ee : beg];
    }
#pragma unroll
    for (int j = 0; j < 4; j++) {
      float2 v = bf2f2(xw2s2[(size_t)idx[j] * 16 + l]);
      cx[j] += val[j] ? v.x : 0.f;
      cy[j] += val[j] ? v.y : 0.f;
    }
  }
  float sx = (cx[0] + cx[1]) + (cx[2] + cx[3]);
  float sy = (cy[0] + cy[1]) + (cy[2] + cy[3]);
  sx += __shfl_xor(sx, 32); sy += __shfl_xor(sy, 32);
  sx += __shfl_xor(sx, 16); sy += __shfl_xor(sy, 16);
  float2 self = bf2f2(xw2s2[(size_t)node * 16 + l]);
  float2 bb = ((const float2*)b2)[l];
  float lx = dd * (sx + self.x) + bb.x;
  float ly = dd * (sy + self.y) + bb.y;
  float m = fmaxf(lx, ly);
#pragma unroll
  for (int o = 8; o > 0; o >>= 1) m = fmaxf(m, __shfl_xor(m, o));
  float s2 = __expf(lx - m) + __expf(ly - m);
#pragma unroll
  for (int o = 8; o > 0; o >>= 1) s2 += __shfl_xor(s2, o);
  float lse = m + __logf(s2);
  if (lane < 16)
    ((float2*)out)[(size_t)node * 16 + l] = make_float2(lx - lse, ly - lse);
}

extern "C" void kernel_launch(void* const* d_in, const int* in_sizes, int n_in,
                              void* d_out, int out_size, void* d_ws, size_t ws_size,
                              hipStream_t stream) {
  (void)n_in; (void)out_size; (void)ws_size;
  const float* x  = (const float*)d_in[0];
  const int*   ei = (const int*)d_in[1];
  const float* w1 = (const float*)d_in[2];
  const float* b1 = (const float*)d_in[3];
  const float* w2 = (const float*)d_in[4];
  const float* b2 = (const float*)d_in[5];
  float* out = (float*)d_out;
  int e = in_sizes[1] / 2;
  const int* src = ei;
  const int* dst = ei + e;

  char* ws = (char*)d_ws;
  int* H              = (int*)(ws + 0x0000000);           // 1MB (256 bins x 1024 blocks)
  int* btot           = (int*)(ws + 0x0100000);           // 1KB
  int* btoff          = (int*)(ws + 0x0100400);           // 1KB
  int* rowptr         = (int*)(ws + 0x0101000);           // 256KB + 4
  float* dinv         = (float*)(ws + 0x0150000);         // 256KB
  unsigned* pk        = (unsigned*)(ws + 0x0200000);      // 4MB (bucket-sorted packed edges)
  int* csr_src        = (int*)(ws + 0x0600000);           // 4MB
  unsigned short* w1t = (unsigned short*)(ws + 0x0A00000);// 128KB
  unsigned short* xw1s= (unsigned short*)(ws + 0x0A20000);// 8MB (bf16)
  unsigned short* xw2s= (unsigned short*)(ws + 0x1220000);// 4MB (bf16)

  int e4 = e / 4;
  k_hist       <<<NEB + 256, 256, 0, stream>>>(dst, H, w1, w1t, e4);
  k_scan_bucket<<<NBUK, 256, 0, stream>>>(H, btot);
  k_scan_tot   <<<1, 256, 0, stream>>>(btot, btoff, rowptr, e);
  k_scatter    <<<NEB, 256, 0, stream>>>(dst, src, H, btoff, pk, e4);
  k_bucket_csr <<<NBUK, 256, 0, stream>>>(pk, btoff, btot, rowptr, csr_src, dinv);
  k_gemm1      <<<N_NODES / 64, 256, 0, stream>>>(x, w1t, dinv, xw1s);
  k_agg1       <<<N_NODES / 4, 256, 0, stream>>>((const unsigned*)xw1s, rowptr, csr_src,
                                                 dinv, b1, w2, xw2s);
  k_agg2       <<<N_NODES / 4, 256, 0, stream>>>((const unsigned*)xw2s, rowptr, csr_src,
                                                 dinv, b2, out);
}

// Round 4
// 489.544 us; speedup vs baseline: 1.1524x; 1.0088x over previous
//
#include <hip/hip_runtime.h>
#include <hip/hip_bf16.h>

#define N_NODES 65536
#define D_IN 1024
#define D_HID 64
#define N_CLS 32
#define NBUK 256   // buckets keyed by dst >> 8
#define NSB 256    // scatter/hist blocks (4096 edges each)

typedef short short8 __attribute__((ext_vector_type(8)));
typedef float floatx4 __attribute__((ext_vector_type(4)));

// ---------- helpers ----------
__device__ __forceinline__ unsigned short f2bf(float f) {
  union { float f; unsigned u; } cv; cv.f = f;
  unsigned r = (cv.u + 0x7FFFu + ((cv.u >> 16) & 1u)) >> 16;
  return (unsigned short)r;
}
__device__ __forceinline__ float2 bf2f2(unsigned v) {
  union { unsigned u; float f; } a, b;
  a.u = v << 16;
  b.u = v & 0xFFFF0000u;
  return make_float2(a.f, b.f);  // (elem 2l, elem 2l+1)
}

// ---------- pass 1: histogram by dst>>8 (blocks 0..255, 4096 edges each, H block-major)
//            + W1^T -> bf16 (blocks 256..511) ----------
__global__ void k_hist_w1t(const int* __restrict__ dst, int* __restrict__ H,
                           const float* __restrict__ w1, unsigned short* __restrict__ w1t,
                           int e4) {
  int b = blockIdx.x, t = threadIdx.x;
  if (b >= NSB) {
    int i = (b - NSB) * 256 + t;  // [0, 65536)
    int k = i / D_HID, n = i % D_HID;
    w1t[n * D_IN + k] = f2bf(w1[i]);
    return;
  }
  __shared__ int hist[NBUK];
  hist[t] = 0;
  __syncthreads();
  const int4* d4 = (const int4*)dst + b * 1024;
#pragma unroll
  for (int p = 0; p < 4; p++) {
    int i4 = b * 1024 + p * 256 + t;
    if (i4 < e4) {
      int4 d = d4[p * 256 + t];
      atomicAdd(&hist[d.x >> 8], 1);
      atomicAdd(&hist[d.y >> 8], 1);
      atomicAdd(&hist[d.z >> 8], 1);
      atomicAdd(&hist[d.w >> 8], 1);
    }
  }
  __syncthreads();
  H[b * NBUK + t] = hist[t];  // block-major: coalesced 1KB write per block
}

// ---------- pass 2a: per-bin exclusive scan over 256 blocks -> Hs (bin-major) ----------
__global__ void k_scan_bin(const int* __restrict__ H, int* __restrict__ Hs,
                           int* __restrict__ btot) {
  int bin = blockIdx.x, t = threadIdx.x;  // t indexes scatter-block b
  int v = H[t * NBUK + bin];
  __shared__ int s[256];
  s[t] = v;
  __syncthreads();
  for (int off = 1; off < 256; off <<= 1) {
    int x = (t >= off) ? s[t - off] : 0;
    __syncthreads();
    s[t] += x;
    __syncthreads();
  }
  Hs[bin * NSB + t] = s[t] - v;  // coalesced per bin
  if (t == 255) btot[bin] = s[255];
}

// ---------- pass 2b: scan bucket totals -> bucket base offsets ----------
__global__ void k_scan_tot(const int* __restrict__ btot, int* __restrict__ btoff,
                           int* __restrict__ rowptr, int e) {
  __shared__ int s[256];
  int t = threadIdx.x;
  int v = btot[t];
  s[t] = v;
  __syncthreads();
  for (int off = 1; off < 256; off <<= 1) {
    int x = (t >= off) ? s[t - off] : 0;
    __syncthreads();
    s[t] += x;
    __syncthreads();
  }
  btoff[t] = s[t] - v;
  if (t == 0) rowptr[N_NODES] = e;
}

// ---------- pass 3 (fused): LDS-staged bucket scatter (blocks 0..255)
//            + GEMM1 unscaled (blocks 256..1279) ----------
__global__ __launch_bounds__(256) void k_scatter_gemm1(
    const int* __restrict__ dst, const int* __restrict__ src,
    const int* __restrict__ Hs, const int* __restrict__ btoff,
    unsigned* __restrict__ pk, int e4,
    const float* __restrict__ x, const unsigned short* __restrict__ w1t,
    unsigned short* __restrict__ xw1s) {
  if (blockIdx.x < NSB) {
    __shared__ int cnt[NBUK], sc[NBUK], cur[NBUK], base2[NBUK];
    __shared__ unsigned stage[4096];
    int b = blockIdx.x, t = threadIdx.x;
    cnt[t] = 0;
    __syncthreads();
    const int4* d4 = (const int4*)dst + b * 1024;
    const int4* s4 = (const int4*)src + b * 1024;
    int4 dv[4], sv[4]; bool ok[4];
#pragma unroll
    for (int p = 0; p < 4; p++) {
      int i4 = b * 1024 + p * 256 + t;
      ok[p] = i4 < e4;
      if (ok[p]) {
        dv[p] = d4[p * 256 + t];
        sv[p] = s4[p * 256 + t];
        atomicAdd(&cnt[dv[p].x >> 8], 1);
        atomicAdd(&cnt[dv[p].y >> 8], 1);
        atomicAdd(&cnt[dv[p].z >> 8], 1);
        atomicAdd(&cnt[dv[p].w >> 8], 1);
      }
    }
    __syncthreads();
    int c = cnt[t];
    sc[t] = c;
    __syncthreads();
    for (int off = 1; off < 256; off <<= 1) {
      int xv = (t >= off) ? sc[t - off] : 0;
      __syncthreads();
      sc[t] += xv;
      __syncthreads();
    }
    int excl = sc[t] - c;
    cur[t] = excl;
    base2[t] = btoff[t] + Hs[t * NSB + b] - excl;  // pk dest = base2[bin] + stagedIdx
    __syncthreads();
    int tot = sc[255];
#pragma unroll
    for (int p = 0; p < 4; p++) {
      if (ok[p]) {
        int d[4] = {dv[p].x, dv[p].y, dv[p].z, dv[p].w};
        int s[4] = {sv[p].x, sv[p].y, sv[p].z, sv[p].w};
#pragma unroll
        for (int j = 0; j < 4; j++) {
          int pos = atomicAdd(&cur[d[j] >> 8], 1);
          stage[pos] = ((unsigned)d[j] << 16) | (unsigned)s[j];
        }
      }
    }
    __syncthreads();
    // flush: staged entries are bucket-grouped -> contiguous full-line runs per bucket
    for (int i = t; i < tot; i += 256) {
      unsigned u = stage[i];
      pk[base2[u >> 24] + i] = u;
    }
    return;
  }
  // ----- GEMM1: xw1 = x @ W1 (UNSCALED), bf16 out; 16 rows/wave -----
  int wave = threadIdx.x >> 6;
  int lane = threadIdx.x & 63;
  int quad = lane >> 4;
  int l16 = lane & 15;
  int rowbase = (blockIdx.x - NSB) * 64 + wave * 16;
  const float* xrow = x + (size_t)(rowbase + l16) * D_IN + quad * 8;
  const unsigned short* bbase = w1t + quad * 8;
  floatx4 acc[4];
#pragma unroll
  for (int nt = 0; nt < 4; nt++) acc[nt] = (floatx4){0.f, 0.f, 0.f, 0.f};
  float4 p0 = *(const float4*)(xrow + 0);
  float4 p1 = *(const float4*)(xrow + 4);
  float4 p2 = *(const float4*)(xrow + 32);
  float4 p3 = *(const float4*)(xrow + 36);
  short8 bf0[4], bf1[4];
#pragma unroll
  for (int nt = 0; nt < 4; nt++) {
    const unsigned short* bp = bbase + (size_t)(nt * 16 + l16) * D_IN;
    bf0[nt] = *(const short8*)(bp);
    bf1[nt] = *(const short8*)(bp + 32);
  }
  for (int k0 = 0; k0 < D_IN; k0 += 64) {
    float4 c0 = p0, c1 = p1, c2 = p2, c3 = p3;
    int kn = (k0 + 64 < D_IN) ? k0 + 64 : k0;
    p0 = *(const float4*)(xrow + kn);
    p1 = *(const float4*)(xrow + kn + 4);
    p2 = *(const float4*)(xrow + kn + 32);
    p3 = *(const float4*)(xrow + kn + 36);
    float av0[8] = {c0.x, c0.y, c0.z, c0.w, c1.x, c1.y, c1.z, c1.w};
    float av1[8] = {c2.x, c2.y, c2.z, c2.w, c3.x, c3.y, c3.z, c3.w};
    short8 af0, af1;
    unsigned* u0 = (unsigned*)&af0;
    unsigned* u1 = (unsigned*)&af1;
#pragma unroll
    for (int j = 0; j < 4; j++) {
      asm("v_cvt_pk_bf16_f32 %0, %1, %2" : "=v"(u0[j]) : "v"(av0[2 * j]), "v"(av0[2 * j + 1]));
      asm("v_cvt_pk_bf16_f32 %0, %1, %2" : "=v"(u1[j]) : "v"(av1[2 * j]), "v"(av1[2 * j + 1]));
    }
#pragma unroll
    for (int nt = 0; nt < 4; nt++)
      acc[nt] = __builtin_amdgcn_mfma_f32_16x16x32_bf16(af0, bf0[nt], acc[nt], 0, 0, 0);
#pragma unroll
    for (int nt = 0; nt < 4; nt++)
      bf0[nt] = *(const short8*)(bbase + (size_t)(nt * 16 + l16) * D_IN + kn);
#pragma unroll
    for (int nt = 0; nt < 4; nt++)
      acc[nt] = __builtin_amdgcn_mfma_f32_16x16x32_bf16(af1, bf1[nt], acc[nt], 0, 0, 0);
#pragma unroll
    for (int nt = 0; nt < 4; nt++)
      bf1[nt] = *(const short8*)(bbase + (size_t)(nt * 16 + l16) * D_IN + kn + 32);
  }
#pragma unroll
  for (int r = 0; r < 4; r++) {
    int row = rowbase + quad * 4 + r;
#pragma unroll
    for (int nt = 0; nt < 4; nt++)
      xw1s[(size_t)row * D_HID + nt * 16 + l16] = f2bf(acc[nt][r]);
  }
}

// ---------- pass 4: per-bucket local CSR (rowptr, dinv, csr_src) ----------
__global__ void k_bucket_csr(const unsigned* __restrict__ pk, const int* __restrict__ btoff,
                             const int* __restrict__ btot, int* __restrict__ rowptr,
                             int* __restrict__ csr_src, float* __restrict__ dinv) {
  __shared__ int cnt[NBUK], sc[NBUK], cur[NBUK];
  int bin = blockIdx.x, t = threadIdx.x;
  cnt[t] = 0;
  __syncthreads();
  int beg = btoff[bin], len = btot[bin];
  for (int i = t; i < len; i += 256)
    atomicAdd(&cnt[(pk[beg + i] >> 16) & 255], 1);
  __syncthreads();
  int c = cnt[t];
  sc[t] = c;
  __syncthreads();
  for (int off = 1; off < 256; off <<= 1) {
    int x = (t >= off) ? sc[t - off] : 0;
    __syncthreads();
    sc[t] += x;
    __syncthreads();
  }
  int excl = sc[t] - c;
  int node = bin * 256 + t;
  rowptr[node] = beg + excl;
  dinv[node] = rsqrtf((float)(c + 1));
  cur[t] = excl;
  __syncthreads();
  for (int i = t; i < len; i += 256) {
    unsigned u = pk[beg + i];
    int p = atomicAdd(&cur[(u >> 16) & 255], 1);
    csr_src[beg + p] = (int)(u & 0xFFFFu);
  }
}

// ---------- agg1 + gemm2 fused; per-edge dinv[src] applied here ----------
__global__ __launch_bounds__(256) void k_agg1(const unsigned* __restrict__ xw1s2,
    const int* __restrict__ rowptr, const int* __restrict__ csr_src,
    const float* __restrict__ dinv, const float* __restrict__ b1,
    const float* __restrict__ w2, unsigned short* __restrict__ xw2s) {
  __shared__ float w2s[D_HID * N_CLS];
  for (int i = threadIdx.x; i < D_HID * N_CLS; i += 256) w2s[i] = w2[i];
  __syncthreads();
  int wave = threadIdx.x >> 6;
  int lane = threadIdx.x & 63;
  int h = lane >> 5, l = lane & 31;
  int node = blockIdx.x * 4 + wave;
  float dd = dinv[node];
  int beg = rowptr[node], end = rowptr[node + 1];
  float cx[8], cy[8];
#pragma unroll
  for (int j = 0; j < 8; j++) { cx[j] = 0.f; cy[j] = 0.f; }
  for (int e = beg + h; e < end; e += 16) {
    int idx[8]; bool val[8];
#pragma unroll
    for (int j = 0; j < 8; j++) {
      int ee = e + 2 * j;
      val[j] = ee < end;
      idx[j] = csr_src[val[j] ? ee : beg];
    }
    float dv[8];
#pragma unroll
    for (int j = 0; j < 8; j++) dv[j] = dinv[idx[j]];
#pragma unroll
    for (int j = 0; j < 8; j++) {
      float2 v = bf2f2(xw1s2[(size_t)idx[j] * 32 + l]);
      float w = val[j] ? dv[j] : 0.f;
      cx[j] += w * v.x;
      cy[j] += w * v.y;
    }
  }
  float sx = ((cx[0] + cx[1]) + (cx[2] + cx[3])) + ((cx[4] + cx[5]) + (cx[6] + cx[7]));
  float sy = ((cy[0] + cy[1]) + (cy[2] + cy[3])) + ((cy[4] + cy[5]) + (cy[6] + cy[7]));
  sx += __shfl_xor(sx, 32);
  sy += __shfl_xor(sy, 32);
  float2 self = bf2f2(xw1s2[(size_t)node * 32 + l]);
  float2 bb = ((const float2*)b1)[l];
  float vx = dd * (sx + dd * self.x) + bb.x;
  float vy = dd * (sy + dd * self.y) + bb.y;
  vx = vx > 0.f ? vx : 0.f;
  vy = vy > 0.f ? vy : 0.f;
  int c = lane & 31;
  float p = 0.f;
#pragma unroll
  for (int kk = 0; kk < 32; kk++) {
    int k = h * 32 + kk;
    float hv = (k & 1) ? __shfl(vy, k >> 1) : __shfl(vx, k >> 1);
    p += hv * w2s[k * N_CLS + c];
  }
  p += __shfl_xor(p, 32);
  if (lane < 32) xw2s[(size_t)node * N_CLS + c] = f2bf(p * dd);
}

// ---------- agg2 + log_softmax ----------
__global__ __launch_bounds__(256) void k_agg2(const unsigned* __restrict__ xw2s2,
    const int* __restrict__ rowptr, const int* __restrict__ csr_src,
    const float* __restrict__ dinv, const float* __restrict__ b2,
    float* __restrict__ out) {
  int wave = threadIdx.x >> 6;
  int lane = threadIdx.x & 63;
  int q = lane >> 4, l = lane & 15;
  int node = blockIdx.x * 4 + wave;
  float dd = dinv[node];
  int beg = rowptr[node], end = rowptr[node + 1];
  float cx[4], cy[4];
#pragma unroll
  for (int j = 0; j < 4; j++) { cx[j] = 0.f; cy[j] = 0.f; }
  for (int e = beg + q; e < end; e += 16) {
    int idx[4]; bool val[4];
#pragma unroll
    for (int j = 0; j < 4; j++) {
      int ee = e + 4 * j;
      val[j] = ee < end;
      idx[j] = csr_src[val[j] ? ee : beg];
    }
#pragma unroll
    for (int j = 0; j < 4; j++) {
      float2 v = bf2f2(xw2s2[(size_t)idx[j] * 16 + l]);
      cx[j] += val[j] ? v.x : 0.f;
      cy[j] += val[j] ? v.y : 0.f;
    }
  }
  float sx = (cx[0] + cx[1]) + (cx[2] + cx[3]);
  float sy = (cy[0] + cy[1]) + (cy[2] + cy[3]);
  sx += __shfl_xor(sx, 32); sy += __shfl_xor(sy, 32);
  sx += __shfl_xor(sx, 16); sy += __shfl_xor(sy, 16);
  float2 self = bf2f2(xw2s2[(size_t)node * 16 + l]);
  float2 bb = ((const float2*)b2)[l];
  float lx = dd * (sx + self.x) + bb.x;
  float ly = dd * (sy + self.y) + bb.y;
  float m = fmaxf(lx, ly);
#pragma unroll
  for (int o = 8; o > 0; o >>= 1) m = fmaxf(m, __shfl_xor(m, o));
  float s2 = __expf(lx - m) + __expf(ly - m);
#pragma unroll
  for (int o = 8; o > 0; o >>= 1) s2 += __shfl_xor(s2, o);
  float lse = m + __logf(s2);
  if (lane < 16)
    ((float2*)out)[(size_t)node * 16 + l] = make_float2(lx - lse, ly - lse);
}

extern "C" void kernel_launch(void* const* d_in, const int* in_sizes, int n_in,
                              void* d_out, int out_size, void* d_ws, size_t ws_size,
                              hipStream_t stream) {
  (void)n_in; (void)out_size; (void)ws_size;
  const float* x  = (const float*)d_in[0];
  const int*   ei = (const int*)d_in[1];
  const float* w1 = (const float*)d_in[2];
  const float* b1 = (const float*)d_in[3];
  const float* w2 = (const float*)d_in[4];
  const float* b2 = (const float*)d_in[5];
  float* out = (float*)d_out;
  int e = in_sizes[1] / 2;
  const int* src = ei;
  const int* dst = ei + e;

  char* ws = (char*)d_ws;
  int* H              = (int*)(ws + 0x0000000);           // 256KB (block-major)
  int* Hs             = (int*)(ws + 0x0040000);           // 256KB (bin-major, scanned)
  int* btot           = (int*)(ws + 0x0080000);           // 1KB
  int* btoff          = (int*)(ws + 0x0080400);           // 1KB
  int* rowptr         = (int*)(ws + 0x0081000);           // 256KB + 4
  float* dinv         = (float*)(ws + 0x00D0000);         // 256KB
  unsigned* pk        = (unsigned*)(ws + 0x0200000);      // 4MB (bucket-sorted packed edges)
  int* csr_src        = (int*)(ws + 0x0600000);           // 4MB
  unsigned short* w1t = (unsigned short*)(ws + 0x0A00000);// 128KB
  unsigned short* xw1s= (unsigned short*)(ws + 0x0A20000);// 8MB (bf16, UNSCALED)
  unsigned short* xw2s= (unsigned short*)(ws + 0x1220000);// 4MB (bf16)

  int e4 = e / 4;
  k_hist_w1t    <<<NSB + 256, 256, 0, stream>>>(dst, H, w1, w1t, e4);
  k_scan_bin    <<<NBUK, 256, 0, stream>>>(H, Hs, btot);
  k_scan_tot    <<<1, 256, 0, stream>>>(btot, btoff, rowptr, e);
  k_scatter_gemm1<<<NSB + 1024, 256, 0, stream>>>(dst, src, Hs, btoff, pk, e4,
                                                  x, w1t, xw1s);
  k_bucket_csr  <<<NBUK, 256, 0, stream>>>(pk, btoff, btot, rowptr, csr_src, dinv);
  k_agg1        <<<N_NODES / 4, 256, 0, stream>>>((const unsigned*)xw1s, rowptr, csr_src,
                                                  dinv, b1, w2, xw2s);
  k_agg2        <<<N_NODES / 4, 256, 0, stream>>>((const unsigned*)xw2s, rowptr, csr_src,
                                                  dinv, b2, out);
}